// Round 11
// baseline (289.625 us; speedup 1.0000x reference)
//
#include <hip/hip_runtime.h>
#include <stdint.h>

#define N_NODES 50000
#define N_EDGES 1600000
#define HID 128
#define NB 196      // dst buckets of 256 nodes
#define CHUNK 8192
#define NCH 196     // ceil(1600000 / 8192)
#define TOT (NB * NCH)
#define NGB 6250    // gather_h0 blocks (N*32/256)
#define NCW 1152    // convert_w blocks
#define NMB 782     // gemm 64-row tiles

typedef float f32x4 __attribute__((ext_vector_type(4)));
typedef float f32x2 __attribute__((ext_vector_type(2)));
typedef short s16x8 __attribute__((ext_vector_type(8)));
typedef unsigned u32x4 __attribute__((ext_vector_type(4)));

__device__ __forceinline__ unsigned short f2bf(float f) {
  unsigned u = __float_as_uint(f);
  u += 0x7fffu + ((u >> 16) & 1u);   // RNE
  return (unsigned short)(u >> 16);
}

__device__ __forceinline__ int block_scan_excl(int v, int t) {
  const int lane = t & 63, wid = t >> 6;
  int incl = v;
  #pragma unroll
  for (int o = 1; o < 64; o <<= 1) {
    int nv = __shfl_up(incl, o);
    if (lane >= o) incl += nv;
  }
  __shared__ int wsum[4];
  if (lane == 63) wsum[wid] = incl;
  __syncthreads();
  int wbase = 0;
  #pragma unroll
  for (int w = 0; w < 3; ++w) if (w < wid) wbase += wsum[w];
  return wbase + incl - v;
}

// ---- pre-kernel: gather_h0 | chunk_hist | convert_w ----
__global__ void k_pre(const int* __restrict__ nid, const float* __restrict__ emb,
                      unsigned short* __restrict__ h0,
                      const int* __restrict__ dst, int* __restrict__ histT,
                      const float* __restrict__ W, const float* __restrict__ Wl,
                      unsigned short* __restrict__ Wt) {
  const int bid = blockIdx.x, t = threadIdx.x;
  if (bid < NGB) {                       // h0 = bf16(emb[node_id])
    int g = bid * 256 + t;
    int i = g >> 5, c = (g & 31) * 4;
    const float4 v = *(const float4*)(emb + (size_t)nid[i] * HID + c);
    ushort4 o;
    o.x = f2bf(v.x); o.y = f2bf(v.y); o.z = f2bf(v.z); o.w = f2bf(v.w);
    *(ushort4*)(h0 + (size_t)i * HID + c) = o;
  } else if (bid < NGB + NCH) {          // per-chunk bucket histogram
    __shared__ int h[NB];
    const int c = bid - NGB;
    if (t < NB) h[t] = 0;
    __syncthreads();
    int base = c * CHUNK;
    #pragma unroll 4
    for (int i = t; i < CHUNK; i += 256) {
      int e = base + i;
      if (e < N_EDGES) atomicAdd(&h[dst[e] >> 8], 1);
    }
    __syncthreads();
    if (t < NB) histT[t * NCH + c] = h[t];
  } else {                               // Wt[l][r][k][d] = W[l][r][d][k]
    int idx = (bid - NGB - NCH) * 256 + t;
    int d  = idx & 127;
    int k  = (idx >> 7) & 127;
    int lr = idx >> 14;
    int l = lr / 9, r = lr - l * 9;
    float v;
    if (r < 8) v = W[((((size_t)l * 8 + r) * 128) + d) * 128 + k];
    else       v = Wl[(((size_t)l * 128) + d) * 128 + k];
    Wt[idx] = f2bf(v);
  }
}

// ---- CSR pass B1: per-bucket chunk-prefix scan (196 blocks, 1 wave each) ----
__global__ void k_scan_buckets(const int* __restrict__ histT, int* __restrict__ curL,
                               int* __restrict__ btot) {
  const int b = blockIdx.x, tid = threadIdx.x;   // 64 threads
  int carry = 0;
  #pragma unroll
  for (int k = 0; k < 4; ++k) {
    int c = k * 64 + tid;
    int v = (c < NCH) ? histT[b * NCH + c] : 0;
    int incl = v;
    #pragma unroll
    for (int o = 1; o < 64; o <<= 1) {
      int nv = __shfl_up(incl, o);
      if (tid >= o) incl += nv;
    }
    if (c < NCH) curL[b * NCH + c] = carry + incl - v;
    carry += __shfl(incl, 63);
  }
  if (tid == 0) btot[b] = carry;
}

// ---- CSR pass B2: scan 196 bucket totals -> bbase ----
__global__ void k_scan_top(const int* __restrict__ btot, int* __restrict__ bbase,
                           int* __restrict__ rowptr) {
  const int t = threadIdx.x;
  int v = (t < NB) ? btot[t] : 0;
  int ex = block_scan_excl(v, t);
  if (t < NB) bbase[t] = ex;
  if (t == 0) { bbase[NB] = N_EDGES; rowptr[N_NODES] = N_EDGES; }
}

// ---- GEMM (all 9 rels per mb-tile, A staged once) | optional scatter role ----
// X[rel][n][k] = sum_d A[n][d] * Wt[rel][k][d]
template <bool SCAT>
__global__ __launch_bounds__(256, 3) void k_gemm9(
    const unsigned short* __restrict__ A,   // [N][128] bf16
    const unsigned short* __restrict__ Bw,  // [9][128][128] bf16 (this layer)
    unsigned short* __restrict__ X,         // [9][N][128] bf16
    const int* __restrict__ src, const int* __restrict__ dst,
    const int* __restrict__ et, const int* __restrict__ curL,
    const int* __restrict__ bbase, unsigned* __restrict__ tmp) {
  __shared__ unsigned char As[16384];   // 64 rows x 256B
  __shared__ unsigned char Ws[32768];   // 128 rows x 256B; reused as C-bounce
  const int t = threadIdx.x;
  if (SCAT && blockIdx.x >= NMB) {      // chunk-local scatter role
    __shared__ int off2[NB];
    const int c = blockIdx.x - NMB;
    if (t < NB) off2[t] = curL[t * NCH + c] + bbase[t];
    __syncthreads();
    int base = c * CHUNK;
    #pragma unroll 4
    for (int i = t; i < CHUNK; i += 256) {
      int e = base + i;
      if (e < N_EDGES) {
        int d = dst[e];
        int pos = atomicAdd(&off2[d >> 8], 1);
        tmp[pos] = ((unsigned)(d & 255) << 19) | ((unsigned)et[e] << 16) | (unsigned)src[e];
      }
    }
    return;
  }
  const int mb = blockIdx.x;
  const int wid = t >> 6, lane = t & 63;
  const int lr = lane & 15, kg = (lane >> 4) * 8;
  // stage A-tile once (16KB), swizzled
  const unsigned char* Asrc = (const unsigned char*)A;
  #pragma unroll
  for (int c = 0; c < 4; ++c) {
    int off = c * 4096 + t * 16;
    int row = off >> 8, ib = off & 255;
    int grow = mb * 64 + row;
    u32x4 va = (u32x4)(0u);
    if (grow < N_NODES) va = *(const u32x4*)(Asrc + (size_t)grow * 256 + ib);
    *(u32x4*)(As + row * 256 + (ib ^ ((row & 7) << 4))) = va;
  }
  // per-thread readback/store coords (constant over rels)
  const int orow = t >> 2;            // 0..63 local row
  const int ocb  = (t & 3) * 64;      // 64B chunk within row
  const int ogrow = mb * 64 + orow;
  for (int rel = 0; rel < 9; ++rel) {
    // stage W_rel (32KB), swizzled
    const unsigned char* Bsrc = (const unsigned char*)(Bw + (size_t)rel * 16384);
    #pragma unroll
    for (int c = 0; c < 8; ++c) {
      int off = c * 4096 + t * 16;
      int row = off >> 8, ib = off & 255;
      *(u32x4*)(Ws + row * 256 + (ib ^ ((row & 7) << 4))) = *(const u32x4*)(Bsrc + off);
    }
    __syncthreads();
    f32x4 acc[8];
    #pragma unroll
    for (int n = 0; n < 8; ++n) acc[n] = (f32x4)(0.f);
    #pragma unroll
    for (int kk = 0; kk < 4; ++kk) {
      const int kb = (kk * 32 + kg) * 2;
      const int rA = wid * 16 + lr;
      s16x8 a = *(const s16x8*)(As + rA * 256 + (kb ^ ((rA & 7) << 4)));
      #pragma unroll
      for (int n = 0; n < 8; ++n) {
        int cc = n * 16 + lr;
        s16x8 b = *(const s16x8*)(Ws + cc * 256 + (kb ^ ((cc & 7) << 4)));
        acc[n] = __builtin_amdgcn_mfma_f32_16x16x32_bf16(a, b, acc[n], 0, 0, 0);
      }
    }
    __syncthreads();   // all waves done reading Ws -> reuse as C bounce
    // acc -> bf16 into Ws[0..16KB), swizzled per row
    {
      const int rowbase = wid * 16 + (lane >> 4) * 4;
      #pragma unroll
      for (int n = 0; n < 8; ++n) {
        int colb = (n * 16 + lr) * 2;
        #pragma unroll
        for (int j = 0; j < 4; ++j) {
          int row = rowbase + j;
          *(unsigned short*)(Ws + row * 256 + (colb ^ ((row & 7) << 4))) = f2bf(acc[n][j]);
        }
      }
    }
    __syncthreads();
    // readback 64B/thread, store full lines (wave = 4KB contiguous)
    if (ogrow < N_NODES) {
      unsigned char* dstp = (unsigned char*)X + ((size_t)rel * N_NODES + ogrow) * 256 + ocb;
      #pragma unroll
      for (int q = 0; q < 4; ++q) {
        u32x4 vv = *(const u32x4*)(Ws + orow * 256 + ((ocb + q * 16) ^ ((orow & 7) << 4)));
        *(u32x4*)(dstp + q * 16) = vv;
      }
    }
    __syncthreads();   // stores' LDS reads done before next rel restages Ws
  }
}

// ---- CSR finalize: per-node counting sort -> rowptr + u32 keys (et*N+src) ----
__global__ void k_bucket_finalize(const unsigned* __restrict__ tmp,
                                  const int* __restrict__ bbase,
                                  int* __restrict__ rowptr,
                                  unsigned* __restrict__ keys) {
  __shared__ int cnt[256];
  __shared__ int off[256];
  const int b = blockIdx.x;
  const int t = threadIdx.x;
  const int s = bbase[b], e = bbase[b + 1];
  cnt[t] = 0;
  __syncthreads();
  for (int i = s + t; i < e; i += 256)
    atomicAdd(&cnt[(tmp[i] >> 19) & 255u], 1);
  __syncthreads();
  int ex = block_scan_excl(cnt[t], t);
  int node = b * 256 + t;
  if (node < N_NODES) rowptr[node] = s + ex;
  off[t] = s + ex;
  __syncthreads();
  for (int i = s + t; i < e; i += 256) {
    unsigned r = tmp[i];
    int pos = atomicAdd(&off[(r >> 19) & 255u], 1);
    keys[pos] = ((r >> 16) & 7u) * N_NODES + (r & 0xffffu);
  }
}

// ---- per-node aggregation over CSR: one wave per node, 16-deep unroll ----
template <bool LAST>
__global__ void k_aggregate(const unsigned short* __restrict__ X,
                            const unsigned* __restrict__ keys,
                            const int* __restrict__ rowptr,
                            const float* __restrict__ bias,
                            void* __restrict__ out) {
  const int t = threadIdx.x;
  const int v = blockIdx.x * 4 + (t >> 6);
  const int lane = t & 63;
  const int start = rowptr[v], end = rowptr[v + 1];
  const unsigned char* Xb = (const unsigned char*)X;
  float a0 = 0.f, a1 = 0.f;
  int e = start;
  const int n16 = start + ((end - start) & ~15);
  for (; e < n16; e += 16) {
    unsigned kk[16], pp[16];
    #pragma unroll
    for (int q = 0; q < 16; ++q) kk[q] = keys[e + q];
    #pragma unroll
    for (int q = 0; q < 16; ++q)
      pp[q] = *(const unsigned*)(Xb + ((size_t)kk[q] << 8) + lane * 4);
    #pragma unroll
    for (int q = 0; q < 16; ++q) {
      a0 += __uint_as_float(pp[q] << 16);
      a1 += __uint_as_float(pp[q] & 0xffff0000u);
    }
  }
  const int n4 = start + ((end - start) & ~3);
  for (; e < n4; e += 4) {
    unsigned kk[4], pp[4];
    #pragma unroll
    for (int q = 0; q < 4; ++q) kk[q] = keys[e + q];
    #pragma unroll
    for (int q = 0; q < 4; ++q)
      pp[q] = *(const unsigned*)(Xb + ((size_t)kk[q] << 8) + lane * 4);
    #pragma unroll
    for (int q = 0; q < 4; ++q) {
      a0 += __uint_as_float(pp[q] << 16);
      a1 += __uint_as_float(pp[q] & 0xffff0000u);
    }
  }
  for (; e < end; ++e) {
    unsigned k0 = keys[e];
    unsigned p0 = *(const unsigned*)(Xb + ((size_t)k0 << 8) + lane * 4);
    a0 += __uint_as_float(p0 << 16); a1 += __uint_as_float(p0 & 0xffff0000u);
  }
  { // self-loop pseudo-relation row
    unsigned p = *(const unsigned*)(Xb + (((size_t)8 * N_NODES + v) << 8) + lane * 4);
    a0 += __uint_as_float(p << 16); a1 += __uint_as_float(p & 0xffff0000u);
  }
  const float2 bb = *(const float2*)(bias + lane * 2);
  a0 += bb.x; a1 += bb.y;
  if (LAST) {
    f32x2 o; o.x = a0; o.y = a1;
    __builtin_nontemporal_store(o, (f32x2*)((float*)out + (size_t)v * 128 + lane * 2));
  } else {
    unsigned po = ((unsigned)f2bf(a1) << 16) | (unsigned)f2bf(a0);
    *(unsigned*)((unsigned short*)out + (size_t)v * 128 + lane * 2) = po;
  }
}

extern "C" void kernel_launch(void* const* d_in, const int* in_sizes, int n_in,
                              void* d_out, int out_size, void* d_ws, size_t ws_size,
                              hipStream_t stream) {
  const int*   nid  = (const int*)d_in[0];
  const int*   src  = (const int*)d_in[1];
  const int*   dst  = (const int*)d_in[2];
  const int*   et   = (const int*)d_in[3];
  const float* emb  = (const float*)d_in[4];
  const float* W    = (const float*)d_in[5];
  const float* Wl   = (const float*)d_in[6];
  const float* bias = (const float*)d_in[7];

  unsigned char* ws = (unsigned char*)d_ws;
  size_t off = 0;
  auto alloc = [&](size_t bytes) {
    void* p = ws + off;
    off = (off + bytes + 255) & ~(size_t)255;
    return p;
  };
  unsigned short* X    = (unsigned short*)alloc((size_t)9 * N_NODES * HID * 2);  // 115.2 MB
  unsigned short* h0   = (unsigned short*)alloc((size_t)N_NODES * HID * 2);      // 12.8 MB
  unsigned short* h1   = (unsigned short*)alloc((size_t)N_NODES * HID * 2);      // 12.8 MB
  unsigned short* Wt   = (unsigned short*)alloc((size_t)2 * 9 * 128 * 128 * 2);  // 0.6 MB
  unsigned*       keys = (unsigned*)alloc((size_t)N_EDGES * 4);                  // 6.4 MB
  int*            rowp = (int*)alloc((size_t)(N_NODES + 1) * 4);
  int*            histT= (int*)alloc((size_t)TOT * 4);                           // 150 KB
  int*            curL = (int*)alloc((size_t)TOT * 4);                           // 150 KB
  int*            btot = (int*)alloc((size_t)NB * 4);
  int*            bbas = (int*)alloc((size_t)(NB + 1) * 4);
  // scatter tmp aliases h1 (dead until aggregate-L0)
  unsigned*       tmp  = (unsigned*)h1;

  k_pre<<<NGB + NCH + NCW, 256, 0, stream>>>(nid, emb, h0, dst, histT, W, Wl, Wt);
  k_scan_buckets<<<NB, 64, 0, stream>>>(histT, curL, btot);
  k_scan_top<<<1, 256, 0, stream>>>(btot, bbas, rowp);
  // gemm layer 0 (782 blocks) + chunk_scatter (196 blocks) fused
  k_gemm9<true><<<NMB + NCH, 256, 0, stream>>>(h0, Wt, X, src, dst, et, curL, bbas, tmp);
  k_bucket_finalize<<<NB, 256, 0, stream>>>(tmp, bbas, rowp, keys);

  const int agrid = N_NODES / 4;                 // 12500, one wave per node
  k_aggregate<false><<<agrid, 256, 0, stream>>>(X, keys, rowp, bias, (void*)h1);
  k_gemm9<false><<<NMB, 256, 0, stream>>>(h1, Wt + (size_t)9 * 128 * 128, X,
                                          src, dst, et, curL, bbas, tmp);
  k_aggregate<true><<<agrid, 256, 0, stream>>>(X, keys, rowp, bias + HID, (void*)d_out);
}

// Round 12
// 280.866 us; speedup vs baseline: 1.0312x; 1.0312x over previous
//
#include <hip/hip_runtime.h>
#include <stdint.h>

#define N_NODES 50000
#define N_EDGES 1600000
#define HID 128
#define NB 196      // dst buckets of 256 nodes
#define CHUNK 8192
#define NCH 196     // ceil(1600000 / 8192)
#define TOT (NB * NCH)
#define NGB 6250    // gather_h0 blocks (N*32/256)
#define NCW 1152    // convert_w blocks
#define NMB 782     // gemm 64-row tiles
#define NGEMM (9 * NMB)   // 7038

typedef float f32x4 __attribute__((ext_vector_type(4)));
typedef float f32x2 __attribute__((ext_vector_type(2)));
typedef short s16x8 __attribute__((ext_vector_type(8)));
typedef unsigned u32x4 __attribute__((ext_vector_type(4)));

__device__ __forceinline__ unsigned short f2bf(float f) {
  unsigned u = __float_as_uint(f);
  u += 0x7fffu + ((u >> 16) & 1u);   // RNE
  return (unsigned short)(u >> 16);
}

__device__ __forceinline__ int block_scan_excl(int v, int t) {
  const int lane = t & 63, wid = t >> 6;
  int incl = v;
  #pragma unroll
  for (int o = 1; o < 64; o <<= 1) {
    int nv = __shfl_up(incl, o);
    if (lane >= o) incl += nv;
  }
  __shared__ int wsum[4];
  if (lane == 63) wsum[wid] = incl;
  __syncthreads();
  int wbase = 0;
  #pragma unroll
  for (int w = 0; w < 3; ++w) if (w < wid) wbase += wsum[w];
  return wbase + incl - v;
}

// ---- pre-kernel: gather_h0 | chunk_hist | convert_w ----
__global__ void k_pre(const int* __restrict__ nid, const float* __restrict__ emb,
                      unsigned short* __restrict__ h0,
                      const int* __restrict__ dst, int* __restrict__ histT,
                      const float* __restrict__ W, const float* __restrict__ Wl,
                      unsigned short* __restrict__ Wt) {
  const int bid = blockIdx.x, t = threadIdx.x;
  if (bid < NGB) {                       // h0 = bf16(emb[node_id])
    int g = bid * 256 + t;
    int i = g >> 5, c = (g & 31) * 4;
    const float4 v = *(const float4*)(emb + (size_t)nid[i] * HID + c);
    ushort4 o;
    o.x = f2bf(v.x); o.y = f2bf(v.y); o.z = f2bf(v.z); o.w = f2bf(v.w);
    *(ushort4*)(h0 + (size_t)i * HID + c) = o;
  } else if (bid < NGB + NCH) {          // per-chunk bucket histogram
    __shared__ int h[NB];
    const int c = bid - NGB;
    if (t < NB) h[t] = 0;
    __syncthreads();
    int base = c * CHUNK;
    #pragma unroll 4
    for (int i = t; i < CHUNK; i += 256) {
      int e = base + i;
      if (e < N_EDGES) atomicAdd(&h[dst[e] >> 8], 1);
    }
    __syncthreads();
    if (t < NB) histT[t * NCH + c] = h[t];
  } else {                               // Wt[l][r][k][d] = W[l][r][d][k]
    int idx = (bid - NGB - NCH) * 256 + t;
    int d  = idx & 127;
    int k  = (idx >> 7) & 127;
    int lr = idx >> 14;
    int l = lr / 9, r = lr - l * 9;
    float v;
    if (r < 8) v = W[((((size_t)l * 8 + r) * 128) + d) * 128 + k];
    else       v = Wl[(((size_t)l * 128) + d) * 128 + k];
    Wt[idx] = f2bf(v);
  }
}

// ---- CSR pass B1: per-bucket chunk-prefix scan (196 blocks, 1 wave each) ----
__global__ void k_scan_buckets(const int* __restrict__ histT, int* __restrict__ curL,
                               int* __restrict__ btot) {
  const int b = blockIdx.x, tid = threadIdx.x;   // 64 threads
  int carry = 0;
  #pragma unroll
  for (int k = 0; k < 4; ++k) {
    int c = k * 64 + tid;
    int v = (c < NCH) ? histT[b * NCH + c] : 0;
    int incl = v;
    #pragma unroll
    for (int o = 1; o < 64; o <<= 1) {
      int nv = __shfl_up(incl, o);
      if (tid >= o) incl += nv;
    }
    if (c < NCH) curL[b * NCH + c] = carry + incl - v;
    carry += __shfl(incl, 63);
  }
  if (tid == 0) btot[b] = carry;
}

// ---- CSR pass B2: scan 196 bucket totals -> bbase ----
__global__ void k_scan_top(const int* __restrict__ btot, int* __restrict__ bbase,
                           int* __restrict__ rowptr) {
  const int t = threadIdx.x;
  int v = (t < NB) ? btot[t] : 0;
  int ex = block_scan_excl(v, t);
  if (t < NB) bbase[t] = ex;
  if (t == 0) { bbase[NB] = N_EDGES; rowptr[N_NODES] = N_EDGES; }
}

// ---- GEMM: one block per (rel, mb), mb-fastest; minimal barriers ----
// X[rel][n][k] = sum_d A[n][d] * Wt[rel][k][d]
template <bool SCAT>
__global__ __launch_bounds__(256, 3) void k_gemm2d(
    const unsigned short* __restrict__ A,   // [N][128] bf16
    const unsigned short* __restrict__ Bw,  // [9][128][128] bf16 (this layer)
    unsigned short* __restrict__ X,         // [9][N][128] bf16
    const int* __restrict__ src, const int* __restrict__ dst,
    const int* __restrict__ et, const int* __restrict__ curL,
    const int* __restrict__ bbase, unsigned* __restrict__ tmp) {
  __shared__ unsigned char As[16384];   // 64 rows x 256B
  __shared__ unsigned char Ws[32768];   // 128 rows x 256B
  const int t = threadIdx.x;
  if (SCAT && blockIdx.x >= NGEMM) {    // chunk-local scatter role
    __shared__ int off2[NB];
    const int c = blockIdx.x - NGEMM;
    if (t < NB) off2[t] = curL[t * NCH + c] + bbase[t];
    __syncthreads();
    int base = c * CHUNK;
    #pragma unroll 4
    for (int i = t; i < CHUNK; i += 256) {
      int e = base + i;
      if (e < N_EDGES) {
        int d = dst[e];
        int pos = atomicAdd(&off2[d >> 8], 1);
        tmp[pos] = ((unsigned)(d & 255) << 19) | ((unsigned)et[e] << 16) | (unsigned)src[e];
      }
    }
    return;
  }
  const int mb  = blockIdx.x % NMB;     // mb fastest: neighbors share rel (W L2-hit)
  const int rel = blockIdx.x / NMB;
  const int wid = t >> 6, lane = t & 63;
  const int lr = lane & 15, kg = (lane >> 4) * 8;
  // stage A-tile (16KB) + W_rel (32KB), swizzled, one barrier
  const unsigned char* Asrc = (const unsigned char*)A;
  #pragma unroll
  for (int c = 0; c < 4; ++c) {
    int off = c * 4096 + t * 16;
    int row = off >> 8, ib = off & 255;
    int grow = mb * 64 + row;
    u32x4 va = (u32x4)(0u);
    if (grow < N_NODES) va = *(const u32x4*)(Asrc + (size_t)grow * 256 + ib);
    *(u32x4*)(As + row * 256 + (ib ^ ((row & 7) << 4))) = va;
  }
  const unsigned char* Bsrc = (const unsigned char*)(Bw + (size_t)rel * 16384);
  #pragma unroll
  for (int c = 0; c < 8; ++c) {
    int off = c * 4096 + t * 16;
    int row = off >> 8, ib = off & 255;
    *(u32x4*)(Ws + row * 256 + (ib ^ ((row & 7) << 4))) = *(const u32x4*)(Bsrc + off);
  }
  __syncthreads();
  f32x4 acc[8];
  #pragma unroll
  for (int n = 0; n < 8; ++n) acc[n] = (f32x4)(0.f);
  #pragma unroll
  for (int kk = 0; kk < 4; ++kk) {
    const int kb = (kk * 32 + kg) * 2;
    const int rA = wid * 16 + lr;
    s16x8 a = *(const s16x8*)(As + rA * 256 + (kb ^ ((rA & 7) << 4)));
    #pragma unroll
    for (int n = 0; n < 8; ++n) {
      int cc = n * 16 + lr;
      s16x8 b = *(const s16x8*)(Ws + cc * 256 + (kb ^ ((cc & 7) << 4)));
      acc[n] = __builtin_amdgcn_mfma_f32_16x16x32_bf16(a, b, acc[n], 0, 0, 0);
    }
  }
  // epilogue: C layout col=lane&15, row=(lane>>4)*4+j; direct stores, no barrier
  const int rbase = mb * 64 + wid * 16 + (lane >> 4) * 4;
  #pragma unroll
  for (int n = 0; n < 8; ++n) {
    int col = n * 16 + lr;
    #pragma unroll
    for (int j = 0; j < 4; ++j) {
      int grow = rbase + j;
      if (grow < N_NODES)
        X[((size_t)rel * N_NODES + grow) * 128 + col] = f2bf(acc[n][j]);
    }
  }
}

// ---- CSR finalize: per-node counting sort -> rowptr + u32 keys (et*N+src) ----
__global__ void k_bucket_finalize(const unsigned* __restrict__ tmp,
                                  const int* __restrict__ bbase,
                                  int* __restrict__ rowptr,
                                  unsigned* __restrict__ keys) {
  __shared__ int cnt[256];
  __shared__ int off[256];
  const int b = blockIdx.x;
  const int t = threadIdx.x;
  const int s = bbase[b], e = bbase[b + 1];
  cnt[t] = 0;
  __syncthreads();
  for (int i = s + t; i < e; i += 256)
    atomicAdd(&cnt[(tmp[i] >> 19) & 255u], 1);
  __syncthreads();
  int ex = block_scan_excl(cnt[t], t);
  int node = b * 256 + t;
  if (node < N_NODES) rowptr[node] = s + ex;
  off[t] = s + ex;
  __syncthreads();
  for (int i = s + t; i < e; i += 256) {
    unsigned r = tmp[i];
    int pos = atomicAdd(&off[(r >> 19) & 255u], 1);
    keys[pos] = ((r >> 16) & 7u) * N_NODES + (r & 0xffffu);
  }
}

// ---- per-node aggregation over CSR: one wave per node, 16-deep unroll ----
template <bool LAST>
__global__ void k_aggregate(const unsigned short* __restrict__ X,
                            const unsigned* __restrict__ keys,
                            const int* __restrict__ rowptr,
                            const float* __restrict__ bias,
                            void* __restrict__ out) {
  const int t = threadIdx.x;
  const int v = blockIdx.x * 4 + (t >> 6);
  const int lane = t & 63;
  const int start = rowptr[v], end = rowptr[v + 1];
  const unsigned char* Xb = (const unsigned char*)X;
  float a0 = 0.f, a1 = 0.f;
  int e = start;
  const int n16 = start + ((end - start) & ~15);
  for (; e < n16; e += 16) {
    unsigned kk[16], pp[16];
    #pragma unroll
    for (int q = 0; q < 16; ++q) kk[q] = keys[e + q];
    #pragma unroll
    for (int q = 0; q < 16; ++q)
      pp[q] = *(const unsigned*)(Xb + ((size_t)kk[q] << 8) + lane * 4);
    #pragma unroll
    for (int q = 0; q < 16; ++q) {
      a0 += __uint_as_float(pp[q] << 16);
      a1 += __uint_as_float(pp[q] & 0xffff0000u);
    }
  }
  const int n4 = start + ((end - start) & ~3);
  for (; e < n4; e += 4) {
    unsigned kk[4], pp[4];
    #pragma unroll
    for (int q = 0; q < 4; ++q) kk[q] = keys[e + q];
    #pragma unroll
    for (int q = 0; q < 4; ++q)
      pp[q] = *(const unsigned*)(Xb + ((size_t)kk[q] << 8) + lane * 4);
    #pragma unroll
    for (int q = 0; q < 4; ++q) {
      a0 += __uint_as_float(pp[q] << 16);
      a1 += __uint_as_float(pp[q] & 0xffff0000u);
    }
  }
  for (; e < end; ++e) {
    unsigned k0 = keys[e];
    unsigned p0 = *(const unsigned*)(Xb + ((size_t)k0 << 8) + lane * 4);
    a0 += __uint_as_float(p0 << 16); a1 += __uint_as_float(p0 & 0xffff0000u);
  }
  { // self-loop pseudo-relation row
    unsigned p = *(const unsigned*)(Xb + (((size_t)8 * N_NODES + v) << 8) + lane * 4);
    a0 += __uint_as_float(p << 16); a1 += __uint_as_float(p & 0xffff0000u);
  }
  const float2 bb = *(const float2*)(bias + lane * 2);
  a0 += bb.x; a1 += bb.y;
  if (LAST) {
    f32x2 o; o.x = a0; o.y = a1;
    __builtin_nontemporal_store(o, (f32x2*)((float*)out + (size_t)v * 128 + lane * 2));
  } else {
    unsigned po = ((unsigned)f2bf(a1) << 16) | (unsigned)f2bf(a0);
    *(unsigned*)((unsigned short*)out + (size_t)v * 128 + lane * 2) = po;
  }
}

extern "C" void kernel_launch(void* const* d_in, const int* in_sizes, int n_in,
                              void* d_out, int out_size, void* d_ws, size_t ws_size,
                              hipStream_t stream) {
  const int*   nid  = (const int*)d_in[0];
  const int*   src  = (const int*)d_in[1];
  const int*   dst  = (const int*)d_in[2];
  const int*   et   = (const int*)d_in[3];
  const float* emb  = (const float*)d_in[4];
  const float* W    = (const float*)d_in[5];
  const float* Wl   = (const float*)d_in[6];
  const float* bias = (const float*)d_in[7];

  unsigned char* ws = (unsigned char*)d_ws;
  size_t off = 0;
  auto alloc = [&](size_t bytes) {
    void* p = ws + off;
    off = (off + bytes + 255) & ~(size_t)255;
    return p;
  };
  unsigned short* X    = (unsigned short*)alloc((size_t)9 * N_NODES * HID * 2);  // 115.2 MB
  unsigned short* h0   = (unsigned short*)alloc((size_t)N_NODES * HID * 2);      // 12.8 MB
  unsigned short* h1   = (unsigned short*)alloc((size_t)N_NODES * HID * 2);      // 12.8 MB
  unsigned short* Wt   = (unsigned short*)alloc((size_t)2 * 9 * 128 * 128 * 2);  // 0.6 MB
  unsigned*       keys = (unsigned*)alloc((size_t)N_EDGES * 4);                  // 6.4 MB
  int*            rowp = (int*)alloc((size_t)(N_NODES + 1) * 4);
  int*            histT= (int*)alloc((size_t)TOT * 4);                           // 150 KB
  int*            curL = (int*)alloc((size_t)TOT * 4);                           // 150 KB
  int*            btot = (int*)alloc((size_t)NB * 4);
  int*            bbas = (int*)alloc((size_t)(NB + 1) * 4);
  // scatter tmp aliases h1 (dead until aggregate-L0)
  unsigned*       tmp  = (unsigned*)h1;

  k_pre<<<NGB + NCH + NCW, 256, 0, stream>>>(nid, emb, h0, dst, histT, W, Wl, Wt);
  k_scan_buckets<<<NB, 64, 0, stream>>>(histT, curL, btot);
  k_scan_top<<<1, 256, 0, stream>>>(btot, bbas, rowp);
  // gemm layer 0 (7038 blocks) + chunk_scatter (196 blocks) fused
  k_gemm2d<true><<<NGEMM + NCH, 256, 0, stream>>>(h0, Wt, X, src, dst, et, curL, bbas, tmp);
  k_bucket_finalize<<<NB, 256, 0, stream>>>(tmp, bbas, rowp, keys);

  const int agrid = N_NODES / 4;                 // 12500, one wave per node
  k_aggregate<false><<<agrid, 256, 0, stream>>>(X, keys, rowp, bias, (void*)h1);
  k_gemm2d<false><<<NGEMM, 256, 0, stream>>>(h1, Wt + (size_t)9 * 128 * 128, X,
                                             src, dst, et, curL, bbas, tmp);
  k_aggregate<true><<<agrid, 256, 0, stream>>>(X, keys, rowp, bias + HID, (void*)d_out);
}